// Round 2
// baseline (213.575 us; speedup 1.0000x reference)
//
#include <hip/hip_runtime.h>

// Problem dims (fixed by reference setup_inputs)
#define BS    32
#define NF    64     // n_feat
#define NN    512    // N
#define JJ    4      // J
#define NOUT  128
#define CC    256    // J*NF
#define NC    16     // n-chunks (one block per chunk, full rows)
#define ROWS  32     // NN/NC rows per chunk
#define ROW4  512    // float4 per (b,n) row (NN*JJ/4; one float4 = one m, j=0..3)
#define NPART NC     // 16 partial-y vectors per batch

// Math: y[b,o] = sum_c fc_w[o,c] * T[b,c] + NN*fc_b[o]
//       T[b, j*NF+f] = sum_m S[b,m,j] * X[b,f,m],  S[b,m,j] = sum_n W[b,n,m,j]
// Linear in W, so each n-chunk block computes a partial y from its partial S.
//
// Fused kernel: grid = BS*NC = 512 blocks, 512 threads (8 waves), 2 blocks/CU.
//   Phase A: stream 32 FULL W-rows. Thread t owns float4-column t, so the
//            block's whole read is one contiguous 256 KB region (rows are
//            adjacent in memory) — maximal sequential run length for HBM.
//   Phase B: 2-way m-split: h = t>>8 covers m-half, (j,f) = (t&3, (t>>2)&63).
//            Sl rows padded to 516 floats (rows 4 banks apart; reads are
//            4-address broadcast -> conflict-free).
//   Phase C: 4-way c-split per o, shfl-reduce over 4 lanes.
__global__ __launch_bounds__(512) void fused_kernel(const float4* __restrict__ W4,
                                                    const float4* __restrict__ X4,
                                                    const float4* __restrict__ fcw4,
                                                    float* __restrict__ Yp) {
    __shared__ __align__(16) float Sl[JJ][ROW4 + 4];  // 516: 2064 B row stride
    __shared__ __align__(16) float Tp[2][CC];
    __shared__ __align__(16) float4 Tsum4[CC / 4];

    int blk = blockIdx.x;           // b*NC + nc
    int nc  = blk & (NC - 1);
    int b   = blk >> 4;             // NC == 16
    int t   = threadIdx.x;          // 0..511 = float4 index within a row = m

    // --- Phase A: stream W rows (contiguous 256 KB per block) ---
    {
        const float4* p = W4 + ((size_t)(b * NN + nc * ROWS)) * ROW4 + t;
        float4 acc = make_float4(0.f, 0.f, 0.f, 0.f);
#pragma unroll 8
        for (int r = 0; r < ROWS; ++r) {
            float4 v = p[(size_t)r * ROW4];
            acc.x += v.x; acc.y += v.y; acc.z += v.z; acc.w += v.w;
        }
        // acc.{x,y,z,w} = partial S[m=t][j=0..3]; consecutive-address writes.
        Sl[0][t] = acc.x; Sl[1][t] = acc.y; Sl[2][t] = acc.z; Sl[3][t] = acc.w;
    }
    __syncthreads();

    // --- Phase B: contract partial S with X; 2-way m-split over h ---
    {
        int j = t & 3, f = (t >> 2) & 63, h = t >> 8;  // h uniform per wave
        const float4* xp = X4 + ((size_t)(b * NF + f)) * (NN / 4) + h * 64;
        const float4* sp = (const float4*)(&Sl[j][0]) + h * 64;
        float tp = 0.f;
#pragma unroll
        for (int i = 0; i < 64; ++i) {   // 64 float4 = 256 m's per half
            float4 xv = xp[i];
            float4 sv = sp[i];
            tp += xv.x * sv.x + xv.y * sv.y + xv.z * sv.z + xv.w * sv.w;
        }
        Tp[h][j * NF + f] = tp;   // channel order c = j*NF + f
    }
    __syncthreads();

    if (t < CC) ((float*)Tsum4)[t] = Tp[0][t] + Tp[1][t];
    __syncthreads();

    // --- Phase C: partial y through fc_w; o = t>>2, quarter k = t&3 ---
    {
        int o = t >> 2, k = t & 3;
        const float4* wp = fcw4 + (size_t)o * (CC / 4) + k * 16;
        float a = 0.f;
#pragma unroll
        for (int u = 0; u < 16; ++u) {
            float4 wv = wp[u];
            float4 tv = Tsum4[k * 16 + u];
            a += wv.x * tv.x + wv.y * tv.y + wv.z * tv.z + wv.w * tv.w;
        }
        a += __shfl_down(a, 2, 4);
        a += __shfl_down(a, 1, 4);
        if (k == 0) Yp[(size_t)blk * NOUT + o] = a;
    }
}

// Tiny final reduce: out[b,o] = NN*fc_b[o] + sum of the 16 block-partials.
// Reads 256 KB (L2-resident), coalesced over o.
__global__ __launch_bounds__(128) void reduce_kernel(const float* __restrict__ Yp,
                                                     const float* __restrict__ fcb,
                                                     float* __restrict__ out) {
    int b = blockIdx.x, o = threadIdx.x;
    float a = (float)NN * fcb[o];
    const float* pp = Yp + (size_t)b * NPART * NOUT + o;
#pragma unroll
    for (int q = 0; q < NPART; ++q) a += pp[q * NOUT];
    out[b * NOUT + o] = a;
}

extern "C" void kernel_launch(void* const* d_in, const int* in_sizes, int n_in,
                              void* d_out, int out_size, void* d_ws, size_t ws_size,
                              hipStream_t stream) {
    // Inputs (setup_inputs order): X, W, fc_w, fc_b, N_batch, mask — all fp32.
    const float4* X4   = (const float4*)d_in[0];
    const float4* W4   = (const float4*)d_in[1];
    const float4* fcw4 = (const float4*)d_in[2];
    const float*  fcb  = (const float*)d_in[3];
    float* out = (float*)d_out;

    // Workspace: 512 partial-y vectors of 128 floats = 256 KB. Fully
    // overwritten by fused_kernel before reduce_kernel reads it (poison-safe).
    float* Yp = (float*)d_ws;

    fused_kernel<<<BS * NC, 512, 0, stream>>>(W4, X4, fcw4, Yp);
    reduce_kernel<<<BS, 128, 0, stream>>>(Yp, fcb, out);
}